// Round 1
// baseline (165.139 us; speedup 1.0000x reference)
//
#include <hip/hip_runtime.h>
#include <cstdint>
#include <cstddef>

// Problem constants: W is [COUT, CIN]; x is [4*4096, CIN]. All I/O fp32.
#define CIN  1024
#define COUT 1024

typedef __attribute__((ext_vector_type(8))) short bf16x8;
typedef __attribute__((ext_vector_type(4))) float f32x4;

// ---------- fp32 -> bf16 (round-to-nearest-even) ----------
__device__ __forceinline__ unsigned short f2bf(float f) {
    union { float f; unsigned int i; } v;
    v.f = f;
    unsigned int u = v.i;
    u += 0x7FFFu + ((u >> 16) & 1u);
    return (unsigned short)(u >> 16);
}

// ---------- kernel 1: zero the fp32 W accumulation buffer (1M floats) ----------
__global__ void zero_f32(float4* __restrict__ p) {
    p[blockIdx.x * 256 + threadIdx.x] = float4{0.f, 0.f, 0.f, 0.f};
}

// ---------- kernel 2: scatter-add fp32 COO values into dense fp32 W ----------
__global__ void scatter_add(const float* __restrict__ vals,
                            const int* __restrict__ rows,
                            const int* __restrict__ cols,
                            float* __restrict__ W, int nnz) {
    int i = blockIdx.x * 256 + threadIdx.x;
    if (i < nnz) {
        atomicAdd(W + (size_t)rows[i] * CIN + cols[i], vals[i]);
    }
}

// ---------- kernel 3: fp32 -> bf16 bulk convert (used for W and for x) ----------
__global__ void cvt_bf16_bulk(const float* __restrict__ src, unsigned short* __restrict__ dst) {
    size_t i = ((size_t)blockIdx.x * 256 + threadIdx.x) * 8;
    float4 v0 = *(const float4*)(src + i);
    float4 v1 = *(const float4*)(src + i + 4);
    union { bf16x8 v; unsigned short u[8]; } w;
    w.u[0] = f2bf(v0.x); w.u[1] = f2bf(v0.y); w.u[2] = f2bf(v0.z); w.u[3] = f2bf(v0.w);
    w.u[4] = f2bf(v1.x); w.u[5] = f2bf(v1.y); w.u[6] = f2bf(v1.z); w.u[7] = f2bf(v1.w);
    *(bf16x8*)(dst + i) = w.v;
}

// ---------- kernel 4: 256x256 8-phase GEMM (T2 swizzle + T3/T4 counted vmcnt + T5) ----
// C[M,N] = A[M,K](bf16) * B[N,K](bf16)^T -> fp32.
// 512 threads = 8 waves (2Mx4N). BK=64. LDS: 2 buffers x (A 256x64 + B 256x64) = 128 KiB.
// Phase = one 128x128 C-quadrant over full BK=64: per wave 4x2 frags x 2 ks = 16 MFMA,
// fed by 12 ds_read_b128. Quadrant order per tile: (A0,B0),(A0,B1),(A1,B0),(A1,B1).
//
// Schedule (derived + WAR/completion-checked for every phase):
//   buf0 holds even K-tiles (consumed phases 1-4), buf1 odd K-tiles (phases 5-8).
//   stage slots: p1 -> odd{A1,B1}(tile 2i+1), p3 -> even{A0}(2i+2), p4 -> even{B0},
//                p5 -> even{A1,B1}, p7 -> odd{A0}(2i+3), p8 -> odd{B0}.
//   Each staged region's last read precedes its stage issue (phase barriers delimit),
//   and vmcnt(4) checkpoints at p4/p8 guarantee completion of everything except the
//   2 halves staged in the two slots after the covered one. Last iteration: vmcnt(0) at p4.
//
// LDS swizzle (carried over, measured 0 bank conflicts): row r (128B = 8 x 16B chunks),
// chunk slot = chunk ^ (r&7); applied on the GLOBAL source side for global_load_lds
// (linear LDS dest = base + tid*16B), and on the chunk index for fragment ds_reads.

#define GLD16(SRC_, DST_)                                                     \
  __builtin_amdgcn_global_load_lds(                                           \
      (const __attribute__((address_space(1))) void*)(SRC_),                  \
      (__attribute__((address_space(3))) void*)(DST_), 16, 0, 0)

#define STAGE_A(BUF_, HALF_, KT_) do {                                        \
    GLD16(pa + (size_t)((HALF_) * 128)      * CIN + (size_t)(KT_) * 64,       \
          As + (BUF_) * 16384 + ((HALF_) * 128) * 64 + tid8);                 \
    GLD16(pa + (size_t)((HALF_) * 128 + 64) * CIN + (size_t)(KT_) * 64,       \
          As + (BUF_) * 16384 + ((HALF_) * 128 + 64) * 64 + tid8);            \
  } while (0)

#define STAGE_B(BUF_, HALF_, KT_) do {                                        \
    GLD16(pb + (size_t)((HALF_) * 128)      * CIN + (size_t)(KT_) * 64,       \
          Bs + (BUF_) * 16384 + ((HALF_) * 128) * 64 + tid8);                 \
    GLD16(pb + (size_t)((HALF_) * 128 + 64) * CIN + (size_t)(KT_) * 64,       \
          Bs + (BUF_) * 16384 + ((HALF_) * 128 + 64) * 64 + tid8);            \
  } while (0)

#define PHASE(BUF_, QA_, QB_, STAGE_BODY_, CKPT_BODY_) do {                   \
    bf16x8 af[2][4];                                                          \
    bf16x8 bfr[2][2];                                                         \
    const unsigned short* abase_ =                                            \
        As + (BUF_) * 16384 + ((QA_) * 128 + wm64) * 64;                      \
    const unsigned short* bbase_ =                                            \
        Bs + (BUF_) * 16384 + ((QB_) * 128 + wn32) * 64;                      \
    _Pragma("unroll")                                                         \
    for (int ks_ = 0; ks_ < 2; ++ks_) {                                       \
      const int cx_ = ((ks_ * 4 + quad) ^ s7) * 8;                            \
      _Pragma("unroll")                                                       \
      for (int mf_ = 0; mf_ < 4; ++mf_)                                       \
        af[ks_][mf_] = *(const bf16x8*)(abase_ + (mf_ * 16 + l16) * 64 + cx_);\
      _Pragma("unroll")                                                       \
      for (int nf_ = 0; nf_ < 2; ++nf_)                                       \
        bfr[ks_][nf_] = *(const bf16x8*)(bbase_ + (nf_ * 16 + l16) * 64 + cx_);\
    }                                                                         \
    STAGE_BODY_                                                               \
    __builtin_amdgcn_s_barrier();                                             \
    asm volatile("s_waitcnt lgkmcnt(0)" ::: "memory");                        \
    __builtin_amdgcn_sched_barrier(0);                                        \
    __builtin_amdgcn_s_setprio(1);                                            \
    _Pragma("unroll")                                                         \
    for (int ks_ = 0; ks_ < 2; ++ks_)                                         \
      _Pragma("unroll")                                                       \
      for (int mf_ = 0; mf_ < 4; ++mf_)                                       \
        _Pragma("unroll")                                                     \
        for (int nf_ = 0; nf_ < 2; ++nf_)                                     \
          acc[QA_][QB_][mf_][nf_] = __builtin_amdgcn_mfma_f32_16x16x32_bf16(  \
              af[ks_][mf_], bfr[ks_][nf_], acc[QA_][QB_][mf_][nf_], 0, 0, 0); \
    __builtin_amdgcn_s_setprio(0);                                            \
    CKPT_BODY_                                                                \
    __builtin_amdgcn_s_barrier();                                             \
  } while (0)

__global__ __launch_bounds__(512, 2) void gemm_8ph(
    const unsigned short* __restrict__ A,   // [M, K] bf16
    const unsigned short* __restrict__ B,   // [N, K] bf16
    float* __restrict__ C,                  // [M, N] fp32
    int M) {
    (void)M;
    constexpr int K = CIN;

    __shared__ __align__(16) unsigned short As[2 * 16384];  // 2 x [256][64]
    __shared__ __align__(16) unsigned short Bs[2 * 16384];

    const int tid  = threadIdx.x;
    const int lane = tid & 63;
    const int w    = tid >> 6;
    const int quad = lane >> 4;
    const int l16  = lane & 15;
    const int s7   = l16 & 7;
    const int wm64 = (w >> 2) * 64;   // wave row offset within a 128x128 quadrant
    const int wn32 = (w & 3) * 32;    // wave col offset within a 128x128 quadrant

    const int rowA0 = blockIdx.x * 256;
    const int rowB0 = blockIdx.y * 256;

    // Staging map (source-side swizzle; LDS dest is linear base + tid*16B).
    const int stg_row = tid >> 3;                 // 0..63 per gload instruction
    const int c_data  = (tid & 7) ^ (stg_row & 7);
    const int tid8    = tid * 8;
    const unsigned short* pa = A + (size_t)(rowA0 + stg_row) * K + c_data * 8;
    const unsigned short* pb = B + (size_t)(rowB0 + stg_row) * K + c_data * 8;

    f32x4 acc[2][2][4][2] = {};

    // ---- prologue: tile0 -> buf0 (all 4 halves), tile1 -> buf1 (A0,B0) ----
    STAGE_A(0, 0, 0); STAGE_A(0, 1, 0); STAGE_B(0, 0, 0); STAGE_B(0, 1, 0);
    STAGE_A(1, 0, 1); STAGE_B(1, 0, 1);
    asm volatile("s_waitcnt vmcnt(4)" ::: "memory");  // tile0 complete; tile1 A0/B0 in flight
    __builtin_amdgcn_s_barrier();

#pragma unroll 1
    for (int i = 0; i < 8; ++i) {          // 16 K-tiles of 64, 2 per iteration
        const int  k1 = 2 * i + 1;
        const int  k2 = 2 * i + 2;
        const int  k3 = 2 * i + 3;
        const bool nl = (i < 7);

        // p1..p4: even tile (buf0)
        PHASE(0, 0, 0, STAGE_A(1, 1, k1); STAGE_B(1, 1, k1); , );
        PHASE(0, 0, 1, , );
        PHASE(0, 1, 0, if (nl) STAGE_A(0, 0, k2); , );
        PHASE(0, 1, 1, if (nl) STAGE_B(0, 0, k2); ,
              if (nl) { asm volatile("s_waitcnt vmcnt(4)" ::: "memory"); }
              else    { asm volatile("s_waitcnt vmcnt(0)" ::: "memory"); } );
        // p5..p8: odd tile (buf1)
        PHASE(1, 0, 0, if (nl) { STAGE_A(0, 1, k2); STAGE_B(0, 1, k2); } , );
        PHASE(1, 0, 1, , );
        PHASE(1, 1, 0, if (nl) STAGE_A(1, 0, k3); , );
        PHASE(1, 1, 1, if (nl) STAGE_B(1, 0, k3); ,
              if (nl) { asm volatile("s_waitcnt vmcnt(4)" ::: "memory"); } );
    }

    // ---- epilogue: C/D layout col = lane&15, row = quad*4 + r (m89-verified) ----
#pragma unroll
    for (int qa = 0; qa < 2; ++qa)
#pragma unroll
        for (int qb = 0; qb < 2; ++qb)
#pragma unroll
            for (int mf = 0; mf < 4; ++mf)
#pragma unroll
                for (int nf = 0; nf < 2; ++nf) {
                    const int row0 = rowA0 + qa * 128 + wm64 + mf * 16 + quad * 4;
                    float* cp = C + (size_t)row0 * COUT
                                  + rowB0 + qb * 128 + wn32 + nf * 16 + l16;
#pragma unroll
                    for (int r = 0; r < 4; ++r)
                        cp[(size_t)r * COUT] = acc[qa][qb][mf][nf][r];
                }
}

extern "C" void kernel_launch(void* const* d_in, const int* in_sizes, int n_in,
                              void* d_out, int out_size, void* d_ws, size_t ws_size,
                              hipStream_t stream) {
    const float* x    = (const float*)d_in[0];   // [M, CIN] fp32
    const float* vals = (const float*)d_in[1];   // [nnz] fp32
    const int*   idx  = (const int*)d_in[2];     // [2, nnz] int32

    float* out = (float*)d_out;                  // [M, COUT] fp32

    const int nnz = in_sizes[2] / 2;
    const int M   = in_sizes[0] / CIN;

    const size_t wf_bytes = (size_t)COUT * CIN * sizeof(float);          // 4 MB
    const size_t wb_bytes = (size_t)COUT * CIN * sizeof(unsigned short); // 2 MB

    float*          Wf = (float*)d_ws;
    unsigned short* Wb = (unsigned short*)((char*)d_ws + wf_bytes);
    unsigned short* Xb = (unsigned short*)((char*)d_ws + wf_bytes + wb_bytes);

    // 1) zero fp32 W (ws is poisoned 0xAA before every call)
    zero_f32<<<dim3(COUT * CIN / (256 * 4)), dim3(256), 0, stream>>>((float4*)Wf);
    // 2) scatter-add duplicates like coalesce()
    scatter_add<<<dim3((nnz + 255) / 256), dim3(256), 0, stream>>>(vals, idx, idx + nnz, Wf, nnz);
    // 3) W -> bf16
    cvt_bf16_bulk<<<dim3(COUT * CIN / (256 * 8)), dim3(256), 0, stream>>>(Wf, Wb);
    // 4) x -> bf16
    cvt_bf16_bulk<<<dim3((unsigned)((size_t)M * CIN / (256 * 8))), dim3(256), 0, stream>>>(x, Xb);
    // 5) 256^2 8-phase GEMM: out = x @ W^T.  grid (64, 4) = 256 blocks = 1/CU.
    gemm_8ph<<<dim3(M / 256, COUT / 256), dim3(512), 0, stream>>>(Xb, Wb, out, M);
}

// Round 2
// 161.251 us; speedup vs baseline: 1.0241x; 1.0241x over previous
//
#include <hip/hip_runtime.h>
#include <cstdint>
#include <cstddef>

// Problem constants: W is [COUT, CIN]; x is [4*4096, CIN]. All I/O fp32.
#define CIN  1024
#define COUT 1024

typedef __attribute__((ext_vector_type(8))) short bf16x8;
typedef __attribute__((ext_vector_type(4))) float f32x4;

// ---------- fp32 -> bf16 (round-to-nearest-even) ----------
__device__ __forceinline__ unsigned short f2bf(float f) {
    union { float f; unsigned int i; } v;
    v.f = f;
    unsigned int u = v.i;
    u += 0x7FFFu + ((u >> 16) & 1u);
    return (unsigned short)(u >> 16);
}

// ---------- kernel 1: zero the fp32 W accumulation buffer (1M floats) ----------
__global__ void zero_f32(float4* __restrict__ p) {
    p[blockIdx.x * 256 + threadIdx.x] = float4{0.f, 0.f, 0.f, 0.f};
}

// ---------- kernel 2: scatter-add fp32 COO values into dense fp32 W ----------
__global__ void scatter_add(const float* __restrict__ vals,
                            const int* __restrict__ rows,
                            const int* __restrict__ cols,
                            float* __restrict__ W, int nnz) {
    int i = blockIdx.x * 256 + threadIdx.x;
    if (i < nnz) {
        atomicAdd(W + (size_t)rows[i] * CIN + cols[i], vals[i]);
    }
}

// ---------- kernel 3: fp32 -> bf16 bulk convert (used for W and for x) ----------
__global__ void cvt_bf16_bulk(const float* __restrict__ src, unsigned short* __restrict__ dst) {
    size_t i = ((size_t)blockIdx.x * 256 + threadIdx.x) * 8;
    float4 v0 = *(const float4*)(src + i);
    float4 v1 = *(const float4*)(src + i + 4);
    union { bf16x8 v; unsigned short u[8]; } w;
    w.u[0] = f2bf(v0.x); w.u[1] = f2bf(v0.y); w.u[2] = f2bf(v0.z); w.u[3] = f2bf(v0.w);
    w.u[4] = f2bf(v1.x); w.u[5] = f2bf(v1.y); w.u[6] = f2bf(v1.z); w.u[7] = f2bf(v1.w);
    *(bf16x8*)(dst + i) = w.v;
}

// ---------- kernel 4: 256x256 8-phase GEMM, v2 schedule ----------
// C[M,N] = A[M,K](bf16) * B[N,K](bf16)^T -> fp32.
// 512 thr = 8 waves (2Mx4N), BK=64, LDS 128 KiB (2 buf x [256][64] x {A,B}).
// Per K-tile: 4 quadrant phases (A0B0)(A0B1)(A1B0)(A1B1); 16 MFMA each.
//
// v2 fixes vs round-1:
//  (a) FRAGMENT PERSISTENCE: af[2][4] reused across 2 phases; bf0/bf1[2][2]
//      persist across the whole K-tile. ds_read_b128 per K-tile per wave:
//      12 (p1) + 4 (p2) + 8 (p3) + 0 (p4) = 24, was 48.
//  (b) EVEN 2-gload/phase STAGING, each half staged the phase after its LDS
//      region's last read, 4-7 phases before its completion deadline:
//        p1: odd(2i+1).B1   p2: odd(2i+1).A1
//        p3: even(2i+2).A0  p4: even(2i+2).B0   K1: vmcnt(4)
//        p5: even(2i+2).B1  p6: even(2i+2).A1
//        p7: odd(2i+3).A0   p8: odd(2i+3).B0    K2: vmcnt(4)
//      Steady state (verified by induction): entering an iteration 4 loads
//      outstanding (odd.A0,B0); K1 completes the odd tile exactly, leaves
//      even.A0,B0; K2 completes the even tile exactly, leaves odd'.A0,B0.
//      WAR: every stage lands in a region whose last ds_read was in a phase
//      strictly before the stage's issuing phase (phase barriers delimit).
//      Last iter (i=7): skip p3..p8 stages, K1 = vmcnt(0), skip K2.
//
// LDS swizzle unchanged (0 bank conflicts measured): row r, 16B-chunk slot =
// chunk ^ (r&7); applied on the GLOBAL source for global_load_lds (linear LDS
// dst = base + tid*16B) and on the chunk index of fragment ds_reads.

#define GLD16(SRC_, DST_)                                                     \
  __builtin_amdgcn_global_load_lds(                                           \
      (const __attribute__((address_space(1))) void*)(SRC_),                  \
      (__attribute__((address_space(3))) void*)(DST_), 16, 0, 0)

#define STAGE_A(BUF_, HALF_, KT_) do {                                        \
    GLD16(pa + (size_t)((HALF_) * 128)      * CIN + (size_t)(KT_) * 64,       \
          As + (BUF_) * 16384 + ((HALF_) * 128) * 64 + tid8);                 \
    GLD16(pa + (size_t)((HALF_) * 128 + 64) * CIN + (size_t)(KT_) * 64,       \
          As + (BUF_) * 16384 + ((HALF_) * 128 + 64) * 64 + tid8);            \
  } while (0)

#define STAGE_B(BUF_, HALF_, KT_) do {                                        \
    GLD16(pb + (size_t)((HALF_) * 128)      * CIN + (size_t)(KT_) * 64,       \
          Bs + (BUF_) * 16384 + ((HALF_) * 128) * 64 + tid8);                 \
    GLD16(pb + (size_t)((HALF_) * 128 + 64) * CIN + (size_t)(KT_) * 64,       \
          Bs + (BUF_) * 16384 + ((HALF_) * 128 + 64) * 64 + tid8);            \
  } while (0)

// Fragment loads (static indices only -> registers).
#define LOAD_A(BUF_, QA_) do {                                                \
    const unsigned short* ab_ = As + (BUF_) * 16384 + ((QA_) * 128 + wm64) * 64; \
    _Pragma("unroll")                                                         \
    for (int ks_ = 0; ks_ < 2; ++ks_) {                                       \
      const int cx_ = ((ks_ * 4 + quad) ^ s7) * 8;                            \
      _Pragma("unroll")                                                       \
      for (int mf_ = 0; mf_ < 4; ++mf_)                                       \
        af[ks_][mf_] = *(const bf16x8*)(ab_ + (mf_ * 16 + l16) * 64 + cx_);   \
    }                                                                         \
  } while (0)

#define LOAD_B(BUF_, QB_, DST_) do {                                          \
    const unsigned short* bb_ = Bs + (BUF_) * 16384 + ((QB_) * 128 + wn32) * 64; \
    _Pragma("unroll")                                                         \
    for (int ks_ = 0; ks_ < 2; ++ks_) {                                       \
      const int cx_ = ((ks_ * 4 + quad) ^ s7) * 8;                            \
      _Pragma("unroll")                                                       \
      for (int nf_ = 0; nf_ < 2; ++nf_)                                       \
        DST_[ks_][nf_] = *(const bf16x8*)(bb_ + (nf_ * 16 + l16) * 64 + cx_); \
    }                                                                         \
  } while (0)

#define MFMA_Q(QA_, QB_, BF_)                                                 \
    _Pragma("unroll")                                                         \
    for (int ks_ = 0; ks_ < 2; ++ks_)                                         \
      _Pragma("unroll")                                                       \
      for (int mf_ = 0; mf_ < 4; ++mf_)                                       \
        _Pragma("unroll")                                                     \
        for (int nf_ = 0; nf_ < 2; ++nf_)                                     \
          acc[QA_][QB_][mf_][nf_] = __builtin_amdgcn_mfma_f32_16x16x32_bf16(  \
              af[ks_][mf_], BF_[ks_][nf_], acc[QA_][QB_][mf_][nf_], 0, 0, 0)

#define SYNC_PRE() do {                                                       \
    __builtin_amdgcn_s_barrier();                                             \
    asm volatile("s_waitcnt lgkmcnt(0)" ::: "memory");                        \
    __builtin_amdgcn_sched_barrier(0);                                        \
    __builtin_amdgcn_s_setprio(1);                                            \
  } while (0)

#define SYNC_POST() __builtin_amdgcn_s_setprio(0)

__global__ __launch_bounds__(512, 2) void gemm_8ph(
    const unsigned short* __restrict__ A,   // [M, K] bf16
    const unsigned short* __restrict__ B,   // [N, K] bf16
    float* __restrict__ C,                  // [M, N] fp32
    int M) {
    (void)M;
    constexpr int K = CIN;

    __shared__ __align__(16) unsigned short As[2 * 16384];  // 2 x [256][64]
    __shared__ __align__(16) unsigned short Bs[2 * 16384];

    const int tid  = threadIdx.x;
    const int lane = tid & 63;
    const int w    = tid >> 6;
    const int quad = lane >> 4;
    const int l16  = lane & 15;
    const int s7   = l16 & 7;
    const int wm64 = (w >> 2) * 64;   // wave row offset within a 128x128 quadrant
    const int wn32 = (w & 3) * 32;    // wave col offset within a 128x128 quadrant

    const int rowA0 = blockIdx.x * 256;
    const int rowB0 = blockIdx.y * 256;

    // Staging map (source-side swizzle; LDS dest linear = base + tid*16B).
    const int stg_row = tid >> 3;
    const int c_data  = (tid & 7) ^ (stg_row & 7);
    const int tid8    = tid * 8;
    const unsigned short* pa = A + (size_t)(rowA0 + stg_row) * K + c_data * 8;
    const unsigned short* pb = B + (size_t)(rowB0 + stg_row) * K + c_data * 8;

    f32x4 acc[2][2][4][2] = {};

    // ---- prologue: tile0 -> buf0 (A0,B0,B1,A1), tile1 -> buf1 (A0,B0) ----
    STAGE_A(0, 0, 0); STAGE_B(0, 0, 0); STAGE_B(0, 1, 0); STAGE_A(0, 1, 0);
    STAGE_A(1, 0, 1); STAGE_B(1, 0, 1);
    asm volatile("s_waitcnt vmcnt(4)" ::: "memory");  // tile0 complete
    __builtin_amdgcn_s_barrier();

#pragma unroll 1
    for (int i = 0; i < 8; ++i) {          // 16 K-tiles of 64, 2 per iteration
        const int  k1 = 2 * i + 1;         // odd tile staged at p1,p2 (B1,A1)
        const int  k2 = 2 * i + 2;
        const int  k3 = 2 * i + 3;
        const bool nl = (i < 7);

        bf16x8 af[2][4];                   // A-frags, reused 2 phases
        bf16x8 bf0[2][2], bf1[2][2];       // B-frags, persist whole K-tile

        // ---- even tile (buf0), quadrants (0,0)(0,1)(1,0)(1,1) ----
        // p1
        LOAD_A(0, 0); LOAD_B(0, 0, bf0);
        STAGE_B(1, 1, k1);
        SYNC_PRE(); MFMA_Q(0, 0, bf0); SYNC_POST();
        __builtin_amdgcn_s_barrier();
        // p2
        LOAD_B(0, 1, bf1);
        STAGE_A(1, 1, k1);
        SYNC_PRE(); MFMA_Q(0, 1, bf1); SYNC_POST();
        __builtin_amdgcn_s_barrier();
        // p3
        LOAD_A(0, 1);
        if (nl) STAGE_A(0, 0, k2);
        SYNC_PRE(); MFMA_Q(1, 0, bf0); SYNC_POST();
        __builtin_amdgcn_s_barrier();
        // p4
        if (nl) STAGE_B(0, 0, k2);
        SYNC_PRE(); MFMA_Q(1, 1, bf1); SYNC_POST();
        if (nl) { asm volatile("s_waitcnt vmcnt(4)" ::: "memory"); }   // K1
        else    { asm volatile("s_waitcnt vmcnt(0)" ::: "memory"); }
        __builtin_amdgcn_s_barrier();

        // ---- odd tile (buf1) ----
        // p5
        LOAD_A(1, 0); LOAD_B(1, 0, bf0);
        if (nl) STAGE_B(0, 1, k2);
        SYNC_PRE(); MFMA_Q(0, 0, bf0); SYNC_POST();
        __builtin_amdgcn_s_barrier();
        // p6
        LOAD_B(1, 1, bf1);
        if (nl) STAGE_A(0, 1, k2);
        SYNC_PRE(); MFMA_Q(0, 1, bf1); SYNC_POST();
        __builtin_amdgcn_s_barrier();
        // p7
        LOAD_A(1, 1);
        if (nl) STAGE_A(1, 0, k3);
        SYNC_PRE(); MFMA_Q(1, 0, bf0); SYNC_POST();
        __builtin_amdgcn_s_barrier();
        // p8
        if (nl) STAGE_B(1, 0, k3);
        SYNC_PRE(); MFMA_Q(1, 1, bf1); SYNC_POST();
        if (nl) { asm volatile("s_waitcnt vmcnt(4)" ::: "memory"); }   // K2
        __builtin_amdgcn_s_barrier();
    }

    // ---- epilogue: C/D layout col = lane&15, row = quad*4 + r (m89-verified) ----
#pragma unroll
    for (int qa = 0; qa < 2; ++qa)
#pragma unroll
        for (int qb = 0; qb < 2; ++qb)
#pragma unroll
            for (int mf = 0; mf < 4; ++mf)
#pragma unroll
                for (int nf = 0; nf < 2; ++nf) {
                    const int row0 = rowA0 + qa * 128 + wm64 + mf * 16 + quad * 4;
                    float* cp = C + (size_t)row0 * COUT
                                  + rowB0 + qb * 128 + wn32 + nf * 16 + l16;
#pragma unroll
                    for (int r = 0; r < 4; ++r)
                        cp[(size_t)r * COUT] = acc[qa][qb][mf][nf][r];
                }
}

extern "C" void kernel_launch(void* const* d_in, const int* in_sizes, int n_in,
                              void* d_out, int out_size, void* d_ws, size_t ws_size,
                              hipStream_t stream) {
    const float* x    = (const float*)d_in[0];   // [M, CIN] fp32
    const float* vals = (const float*)d_in[1];   // [nnz] fp32
    const int*   idx  = (const int*)d_in[2];     // [2, nnz] int32

    float* out = (float*)d_out;                  // [M, COUT] fp32

    const int nnz = in_sizes[2] / 2;
    const int M   = in_sizes[0] / CIN;

    const size_t wf_bytes = (size_t)COUT * CIN * sizeof(float);          // 4 MB
    const size_t wb_bytes = (size_t)COUT * CIN * sizeof(unsigned short); // 2 MB

    float*          Wf = (float*)d_ws;
    unsigned short* Wb = (unsigned short*)((char*)d_ws + wf_bytes);
    unsigned short* Xb = (unsigned short*)((char*)d_ws + wf_bytes + wb_bytes);

    // 1) zero fp32 W (ws is poisoned 0xAA before every call)
    zero_f32<<<dim3(COUT * CIN / (256 * 4)), dim3(256), 0, stream>>>((float4*)Wf);
    // 2) scatter-add duplicates like coalesce()
    scatter_add<<<dim3((nnz + 255) / 256), dim3(256), 0, stream>>>(vals, idx, idx + nnz, Wf, nnz);
    // 3) W -> bf16
    cvt_bf16_bulk<<<dim3(COUT * CIN / (256 * 8)), dim3(256), 0, stream>>>(Wf, Wb);
    // 4) x -> bf16
    cvt_bf16_bulk<<<dim3((unsigned)((size_t)M * CIN / (256 * 8))), dim3(256), 0, stream>>>(x, Xb);
    // 5) 256^2 8-phase GEMM: out = x @ W^T.  grid (64, 4) = 256 blocks = 1/CU.
    gemm_8ph<<<dim3(M / 256, COUT / 256), dim3(512), 0, stream>>>(Xb, Wb, out, M);
}